// Round 7
// baseline (66.620 us; speedup 1.0000x reference)
//
#include <hip/hip_runtime.h>
#include <hip/hip_bf16.h>

#define B_   8
#define SQ_  2048
#define SK_  2048
#define D_   128

typedef __attribute__((ext_vector_type(8))) _Float16 f16x8;
typedef __attribute__((ext_vector_type(4))) _Float16 f16x4;
typedef __attribute__((ext_vector_type(4))) float    f32x4;

// Fragment-major layouts (f16), lane l, hi = l>>4, ql = l&15:
//  Qf[b][qt:128][ks:4][l][8] : elem (q = qt*16+ql, d = ks*32+hi*8+j)   (B-frag)
//  Kf[b][kt:128][ks:4][l][8] : elem (k = kt*16+ql, d = ks*32+hi*8+j)   (A-frag)
//  Vf[b][kt:64][dt:8][l][8]  : elem (k = kt*32+hi*8+j, d = dt*16+ql)   (B-frag, PV)
//  RZ[qt:128][kt:64][l][8]   : elem (q = qt*16+ql, k = kt*32+hi*8+j)   (A-frag, PV)
#define QK_BSTRIDE (128 * 4 * 64 * 8)   // 262144 elems per batch
#define VF_BSTRIDE (64 * 8 * 64 * 8)    // 262144 elems per batch

__device__ __forceinline__ void dma16(const void* g, void* l) {
    __builtin_amdgcn_global_load_lds(
        (const __attribute__((address_space(1))) unsigned int*)g,
        (__attribute__((address_space(3))) unsigned int*)l, 16, 0, 0);
}

// ---------------------------------------------------------------------------
// prep: blocks 0..2047 -> Q,K fp32 -> fragment-major f16
//       blocks 2048..2303 -> V fp32 -> PV-B-fragment-major f16
// ---------------------------------------------------------------------------
__global__ __launch_bounds__(256)
void prep(const float* __restrict__ Q, const float* __restrict__ K,
          const float* __restrict__ V,
          _Float16* __restrict__ Qf, _Float16* __restrict__ Kf,
          _Float16* __restrict__ Vf) {
    __shared__ _Float16 T[64][136];
    const int bid = blockIdx.x;
    if (bid < 2048) {
        const float* src = (bid >= 1024) ? K : Q;
        _Float16*    dst = (bid >= 1024) ? Kf : Qf;
        int gid = (bid & 1023) * 256 + threadIdx.x;     // 0..262143
        int l  = gid & 63;
        int ks = (gid >> 6) & 3;
        int t  = (gid >> 8) & 127;
        int b  = gid >> 15;
        const float* p = src + ((size_t)b * 2048 + t * 16 + (l & 15)) * 128
                             + ks * 32 + (l >> 4) * 8;
        f32x4 a = *(const f32x4*)p;
        f32x4 c = *(const f32x4*)(p + 4);
        f16x8 r;
        r[0] = (_Float16)a[0]; r[1] = (_Float16)a[1];
        r[2] = (_Float16)a[2]; r[3] = (_Float16)a[3];
        r[4] = (_Float16)c[0]; r[5] = (_Float16)c[1];
        r[6] = (_Float16)c[2]; r[7] = (_Float16)c[3];
        *(f16x8*)(dst + (size_t)gid * 8) = r;
    } else {
        const int vb = bid - 2048;           // 0..255
        const int b  = vb >> 5;
        const int kb = vb & 31;
        const int t  = threadIdx.x;
        const int row = t >> 2, c0 = (t & 3) * 32;
        const float* src = V + ((size_t)b * SK_ + kb * 64 + row) * D_ + c0;
#pragma unroll
        for (int u = 0; u < 8; ++u) {
            f32x4 v = *(const f32x4*)(src + u * 4);
            f16x4 h;
            h[0] = (_Float16)v[0]; h[1] = (_Float16)v[1];
            h[2] = (_Float16)v[2]; h[3] = (_Float16)v[3];
            *(f16x4*)&T[row][c0 + u * 4] = h;
        }
        __syncthreads();
#pragma unroll
        for (int u = 0; u < 4; ++u) {
            int s   = u * 256 + t;            // 0..1023
            int l   = s & 63;
            int dt  = (s >> 6) & 7;
            int ktl = s >> 9;                 // 0..1
            int hi  = l >> 4, ql = l & 15;
            f16x8 r;
#pragma unroll
            for (int j = 0; j < 8; ++j) r[j] = T[ktl * 32 + hi * 8 + j][dt * 16 + ql];
            *(f16x8*)(Vf + (((size_t)b * 64 + kb * 2 + ktl) * 8 + dt) * 512 + (size_t)l * 8) = r;
        }
    }
}

// ---------------------------------------------------------------------------
// Phase 1: RZ[q][k] = 1 / sum_b exp(S_b[q,k]/128) in PV-A-frag-major layout.
// grid 1024 (32 qtiles x 32 ktiles), block 512 (8 waves = 8 batches).
// ---------------------------------------------------------------------------
__global__ __launch_bounds__(512, 4)
void zred(const _Float16* __restrict__ Qf, const _Float16* __restrict__ Kf,
          _Float16* __restrict__ RZ) {
    __shared__ __attribute__((aligned(16))) _Float16 E[8][64][64];  // 64 KB
    const int bid   = blockIdx.x;
    const int qtile = bid >> 5;
    const int ktile = bid & 31;
    const int b  = threadIdx.x >> 6;
    const int l  = threadIdx.x & 63;
    const int hi = l >> 4, ql = l & 15;

    const _Float16* Qb = Qf + (size_t)b * QK_BSTRIDE;
    const _Float16* Kb = Kf + (size_t)b * QK_BSTRIDE;

    // swapped S^T = mfma(K, Q): lane holds k = kk*16+hi*4+r, q = qq*16+ql
    f32x4 s[4][4] = {};
#pragma unroll
    for (int ks = 0; ks < 4; ++ks) {
        f16x8 kf[4];
#pragma unroll
        for (int kk = 0; kk < 4; ++kk)
            kf[kk] = *(const f16x8*)(Kb + ((((size_t)ktile * 4 + kk) * 4 + ks) * 64 + l) * 8);
#pragma unroll
        for (int qq = 0; qq < 4; ++qq) {
            f16x8 qv = *(const f16x8*)(Qb + ((((size_t)qtile * 4 + qq) * 4 + ks) * 64 + l) * 8);
#pragma unroll
            for (int kk = 0; kk < 4; ++kk)
                s[kk][qq] = __builtin_amdgcn_mfma_f32_16x16x32_f16(kf[kk], qv, s[kk][qq], 0, 0, 0);
        }
    }

    // E[b][q][k] = exp(S/128), 16B-granule XOR swizzle on k-group
    f16x4* E4 = (f16x4*)&E[0][0][0];
#pragma unroll
    for (int kk = 0; kk < 4; ++kk)
#pragma unroll
        for (int qq = 0; qq < 4; ++qq) {
            f16x4 e;
#pragma unroll
            for (int r = 0; r < 4; ++r)
                e[r] = (_Float16)__expf(s[kk][qq][r] * 0.0078125f);
            int q = qq * 16 + ql;
            int k = kk * 16 + hi * 4;
            int g16 = ((b * 64 + q) << 3) + ((k >> 3) ^ (q & 7));
            E4[g16 * 2 + ((k >> 2) & 1)] = e;
        }
    __syncthreads();

    // thread -> PV-A-frag slot: (ktl, qq2, lane)
    const int t    = threadIdx.x;
    const int ktl  = t >> 8;             // 0..1
    const int qq2  = (t >> 6) & 3;       // 0..3
    const int l2   = t & 63;
    const int hi2  = l2 >> 4, ql2 = l2 & 15;
    const int q_loc  = qq2 * 16 + ql2;
    const int k0_loc = ktl * 32 + hi2 * 8;
    const f16x8* E8  = (const f16x8*)&E[0][0][0];
    const int eidx   = (q_loc << 3) + ((k0_loc >> 3) ^ (q_loc & 7));

    f16x8 z = E8[eidx];
#pragma unroll
    for (int bb = 1; bb < 8; ++bb) z = z + E8[bb * 512 + eidx];

    f16x8 rz8;
#pragma unroll
    for (int j = 0; j < 8; ++j)
        rz8[j] = (_Float16)__builtin_amdgcn_rcpf((float)z[j]);

    // RZ[qt][kt32][l][8], qt = qtile*4+qq2, kt32 = ktile*2+ktl, lane = l2
    *(f16x8*)(RZ + (((size_t)(qtile * 4 + qq2)) * 64 + (ktile * 2 + ktl)) * 512
                 + (size_t)l2 * 8) = rz8;
}

// ---------------------------------------------------------------------------
// Phase 2 (fused): O_b = (exp(QK^T/128) * rz) @ V_b, all operands DMA-staged.
// grid 256 = (b 8) x (mt 32: 64-q tile), block 512 (8 waves).
// Per iter (64 k): stage K 16KB + V 16KB + rz 8KB (40 x dma16, triple-buffer,
// counted vmcnt); QK waves = (kk, qq-pair); exp -> E (8KB XOR-swizzled, dbuf);
// PV waves = (qq-pair, d-half, ktl) with epilogue LDS reduce over ktl.
// ---------------------------------------------------------------------------
__global__ __launch_bounds__(512)
void fav(const _Float16* __restrict__ Qf, const _Float16* __restrict__ Kf,
         const _Float16* __restrict__ Vf, const _Float16* __restrict__ RZ,
         float* __restrict__ out) {
    // 3 stage bufs x 40KB (20480 f16) + 2 E bufs x 8KB (4096 f16) = 136 KB
    __shared__ __attribute__((aligned(16))) _Float16 lds[3 * 20480 + 2 * 4096];

    const int bid = blockIdx.x;
    const int b   = bid & 7;             // batch -> XCD pinned
    const int mt  = bid >> 3;            // 64-q tile
    const int w   = threadIdx.x >> 6;
    const int l   = threadIdx.x & 63;
    const int hi  = l >> 4, ql = l & 15;
    // QK role
    const int kkq = w >> 1, qqp = w & 1;
    // PV role
    const int pqqp = w >> 2, pdth = (w >> 1) & 1, pktl = w & 1;

    const _Float16* Qb = Qf + (size_t)b * QK_BSTRIDE;
    const _Float16* Kb = Kf + (size_t)b * QK_BSTRIDE;
    const _Float16* Vb = Vf + (size_t)b * VF_BSTRIDE;

    // hoist Q fragments (loop-invariant): qq = qqp*2 + i
    f16x8 qf[2][4];
#pragma unroll
    for (int i = 0; i < 2; ++i)
#pragma unroll
        for (int ks = 0; ks < 4; ++ks)
            qf[i][ks] = *(const f16x8*)(Qb + ((((size_t)(mt * 4 + qqp * 2 + i)) * 4 + ks) * 64 + l) * 8);

#define STAGE(bufi, it2) do {                                                  \
    _Float16* dst0 = (_Float16*)lds + (size_t)(bufi) * 20480;                  \
    _Pragma("unroll")                                                          \
    for (int u = 0; u < 5; ++u) {                                              \
        int c = w * 5 + u;                                                     \
        const _Float16* srcp;                                                  \
        if (c < 16)                                                            \
            srcp = Kb + (((size_t)((it2) * 4 + (c >> 2))) * 4 + (c & 3)) * 512 + (size_t)l * 8; \
        else if (c < 32) {                                                     \
            int cv = c - 16;                                                   \
            srcp = Vb + (((size_t)((it2) * 2 + (cv >> 3))) * 8 + (cv & 7)) * 512 + (size_t)l * 8; \
        } else {                                                               \
            int cr = c - 32;                                                   \
            srcp = RZ + (((size_t)(mt * 4 + (cr >> 1))) * 64 + ((it2) * 2 + (cr & 1))) * 512 + (size_t)l * 8; \
        }                                                                      \
        dma16(srcp, dst0 + c * 512);                                           \
    }                                                                          \
} while (0)

    f32x4 acc[2][4] = {};
    STAGE(0, 0);
    STAGE(1, 1);

    for (int it = 0; it < 32; ++it) {
        if (it < 31) asm volatile("s_waitcnt vmcnt(5)" ::: "memory");
        else         asm volatile("s_waitcnt vmcnt(0)" ::: "memory");
        __builtin_amdgcn_s_barrier();                 // stage buf[it%3] ready
        __builtin_amdgcn_sched_barrier(0);
        if (it < 30) STAGE((it + 2) % 3, it + 2);     // safe: all reads of this
                                                      // buf finished pre-barrier
        const _Float16* SB = (const _Float16*)lds + (size_t)(it % 3) * 20480;

        // --- QK: S^T(kkq-tile, qq pair) = mfma(K, Q), K=128 ---
        f32x4 s0 = {}, s1 = {};
#pragma unroll
        for (int ks = 0; ks < 4; ++ks) {
            f16x8 kf8 = *(const f16x8*)(SB + (kkq * 4 + ks) * 512 + l * 8);
            s0 = __builtin_amdgcn_mfma_f32_16x16x32_f16(kf8, qf[0][ks], s0, 0, 0, 0);
            s1 = __builtin_amdgcn_mfma_f32_16x16x32_f16(kf8, qf[1][ks], s1, 0, 0, 0);
        }

        // --- E = exp(S/128) -> swizzled LDS (dbuf) ---
        _Float16* Ebuf = (_Float16*)lds + 61440 + (it & 1) * 4096;
        f16x4* E4 = (f16x4*)Ebuf;
        {
            const int k_loc = kkq * 16 + hi * 4;
            f16x4 e0, e1;
#pragma unroll
            for (int r = 0; r < 4; ++r) {
                e0[r] = (_Float16)__expf(s0[r] * 0.0078125f);
                e1[r] = (_Float16)__expf(s1[r] * 0.0078125f);
            }
            int q0 = (qqp * 2 + 0) * 16 + ql;
            int q1 = (qqp * 2 + 1) * 16 + ql;
            E4[(((q0 << 3) + ((k_loc >> 3) ^ (q0 & 7))) << 1) + ((k_loc >> 2) & 1)] = e0;
            E4[(((q1 << 3) + ((k_loc >> 3) ^ (q1 & 7))) << 1) + ((k_loc >> 2) & 1)] = e1;
        }
        asm volatile("s_waitcnt lgkmcnt(0)" ::: "memory");
        __builtin_amdgcn_s_barrier();                 // E complete (vmcnt NOT drained)
        __builtin_amdgcn_sched_barrier(0);

        // --- PV: P = E * rz (A-frags), O += P @ V ---
        const f16x8* E8 = (const f16x8*)Ebuf;
        f16x8 p8[2];
#pragma unroll
        for (int i = 0; i < 2; ++i) {
            int q_loc = (pqqp * 2 + i) * 16 + ql;
            int k0    = pktl * 32 + hi * 8;
            f16x8 e8  = E8[(q_loc << 3) + ((k0 >> 3) ^ (q_loc & 7))];
            f16x8 rz8 = *(const f16x8*)(SB + (32 + (pqqp * 2 + i) * 2 + pktl) * 512 + l * 8);
            p8[i] = e8 * rz8;
        }
#pragma unroll
        for (int j = 0; j < 4; ++j) {
            f16x8 v8 = *(const f16x8*)(SB + (16 + pktl * 8 + pdth * 4 + j) * 512 + l * 8);
            acc[0][j] = __builtin_amdgcn_mfma_f32_16x16x32_f16(p8[0], v8, acc[0][j], 0, 0, 0);
            acc[1][j] = __builtin_amdgcn_mfma_f32_16x16x32_f16(p8[1], v8, acc[1][j], 0, 0, 0);
        }
    }
#undef STAGE

    // --- epilogue: reduce ktl partials via LDS, then coalesced-ish store ---
    __syncthreads();
    float* OB = (float*)lds;   // 32 frags x 1KB = 32 KB (stage area is dead)
    if (pktl == 1) {
#pragma unroll
        for (int i = 0; i < 2; ++i)
#pragma unroll
            for (int j = 0; j < 4; ++j)
                *(f32x4*)(OB + (size_t)(((pqqp * 2 + i) * 8) + pdth * 4 + j) * 256 + l * 4)
                    = acc[i][j];
    }
    __syncthreads();
    if (pktl == 0) {
#pragma unroll
        for (int i = 0; i < 2; ++i)
#pragma unroll
            for (int j = 0; j < 4; ++j) {
                f32x4 o = acc[i][j]
                        + *(const f32x4*)(OB + (size_t)(((pqqp * 2 + i) * 8) + pdth * 4 + j) * 256 + l * 4);
#pragma unroll
                for (int r = 0; r < 4; ++r)
                    out[((size_t)b * SQ_ + mt * 64 + (pqqp * 2 + i) * 16 + hi * 4 + r) * D_
                        + (pdth * 4 + j) * 16 + ql] = o[r];
            }
    }
}

// ---------------------------------------------------------------------------
extern "C" void kernel_launch(void* const* d_in, const int* in_sizes, int n_in,
                              void* d_out, int out_size, void* d_ws, size_t ws_size,
                              hipStream_t stream) {
    const float* Q = (const float*)d_in[0];
    const float* K = (const float*)d_in[1];
    const float* V = (const float*)d_in[2];
    float* out = (float*)d_out;

    _Float16* Qf = (_Float16*)d_ws;                       // 4 MB
    _Float16* Kf = Qf + (size_t)B_ * QK_BSTRIDE;          // 4 MB
    _Float16* Vf = Kf + (size_t)B_ * QK_BSTRIDE;          // 4 MB
    _Float16* RZ = Vf + (size_t)B_ * VF_BSTRIDE;          // 8 MB (20 MB total)

    prep<<<2048 + 256, 256, 0, stream>>>(Q, K, V, Qf, Kf, Vf);
    zred<<<1024, 512, 0, stream>>>(Qf, Kf, RZ);
    fav<<<256, 512, 0, stream>>>(Qf, Kf, Vf, RZ, out);
}

// Round 8
// 59.110 us; speedup vs baseline: 1.1271x; 1.1271x over previous
//
#include <hip/hip_runtime.h>
#include <hip/hip_bf16.h>

#define B_   8
#define SQ_  2048
#define SK_  2048
#define D_   128

typedef __attribute__((ext_vector_type(8))) _Float16 f16x8;
typedef __attribute__((ext_vector_type(4))) _Float16 f16x4;
typedef __attribute__((ext_vector_type(4))) float    f32x4;

// Fragment-major layouts (f16), lane l, hi = l>>4, ql = l&15:
//  Qf[b][qt:128][ks:4][l][8] : elem (q = qt*16+ql, d = ks*32+hi*8+j)  PRE-SCALED log2e/8
//  Kf[b][kt:128][ks:4][l][8] : elem (k = kt*16+ql, d = ks*32+hi*8+j)  PRE-SCALED 1/16
//  Vf[b][kt:64][dt:8][l][8]  : elem (k = kt*32+hi*8+j, d = dt*16+ql)   (B-frag for PV)
//  Pf[b][qtl][kt:64][l][8]   : elem (q = qtl*16+ql, k = kt*32+hi*8+j)  (A-frag for PV)
// => S(mfma) = (Q.K) * log2e/128, so exp(QK/128) = exp2(S): one v_exp_f32.
#define QK_BSTRIDE (128 * 4 * 64 * 8)   // 262144 elems per batch
#define VF_BSTRIDE (64 * 8 * 64 * 8)    // 262144 elems per batch

__device__ __forceinline__ void dma16(const void* g, void* l) {
    __builtin_amdgcn_global_load_lds(
        (const __attribute__((address_space(1))) unsigned int*)g,
        (__attribute__((address_space(3))) unsigned int*)l, 16, 0, 0);
}

__device__ __forceinline__ float fast_exp2(float x) {
#if __has_builtin(__builtin_amdgcn_exp2f)
    return __builtin_amdgcn_exp2f(x);
#else
    return __expf(x * 0.6931471805599453f);
#endif
}

// ---------------------------------------------------------------------------
// prep: blocks 0..2047 -> Q,K fp32 -> fragment-major f16 (pre-scaled)
//       blocks 2048..2303 -> V fp32 -> PV-B-fragment-major f16
// ---------------------------------------------------------------------------
__global__ __launch_bounds__(256)
void prep(const float* __restrict__ Q, const float* __restrict__ K,
          const float* __restrict__ V,
          _Float16* __restrict__ Qf, _Float16* __restrict__ Kf,
          _Float16* __restrict__ Vf) {
    __shared__ _Float16 T[64][136];
    const int bid = blockIdx.x;
    if (bid < 2048) {
        const float* src = (bid >= 1024) ? K : Q;
        _Float16*    dst = (bid >= 1024) ? Kf : Qf;
        // Q *= log2e/8, K *= 1/16  => product carries log2e/128
        const float sc = (bid >= 1024) ? 0.0625f : 0.18033688f;
        int gid = (bid & 1023) * 256 + threadIdx.x;     // 0..262143
        int l  = gid & 63;
        int ks = (gid >> 6) & 3;
        int t  = (gid >> 8) & 127;
        int b  = gid >> 15;
        const float* p = src + ((size_t)b * 2048 + t * 16 + (l & 15)) * 128
                             + ks * 32 + (l >> 4) * 8;
        f32x4 a = *(const f32x4*)p;
        f32x4 c = *(const f32x4*)(p + 4);
        f16x8 r;
        r[0] = (_Float16)(a[0] * sc); r[1] = (_Float16)(a[1] * sc);
        r[2] = (_Float16)(a[2] * sc); r[3] = (_Float16)(a[3] * sc);
        r[4] = (_Float16)(c[0] * sc); r[5] = (_Float16)(c[1] * sc);
        r[6] = (_Float16)(c[2] * sc); r[7] = (_Float16)(c[3] * sc);
        *(f16x8*)(dst + (size_t)gid * 8) = r;
    } else {
        const int vb = bid - 2048;           // 0..255
        const int b  = vb >> 5;
        const int kb = vb & 31;
        const int t  = threadIdx.x;
        const int row = t >> 2, c0 = (t & 3) * 32;
        const float* src = V + ((size_t)b * SK_ + kb * 64 + row) * D_ + c0;
#pragma unroll
        for (int u = 0; u < 8; ++u) {
            f32x4 v = *(const f32x4*)(src + u * 4);
            f16x4 h;
            h[0] = (_Float16)v[0]; h[1] = (_Float16)v[1];
            h[2] = (_Float16)v[2]; h[3] = (_Float16)v[3];
            *(f16x4*)&T[row][c0 + u * 4] = h;
        }
        __syncthreads();
#pragma unroll
        for (int u = 0; u < 4; ++u) {
            int s   = u * 256 + t;            // 0..1023
            int l   = s & 63;
            int dt  = (s >> 6) & 7;
            int ktl = s >> 9;                 // 0..1
            int hi  = l >> 4, ql = l & 15;
            f16x8 r;
#pragma unroll
            for (int j = 0; j < 8; ++j) r[j] = T[ktl * 32 + hi * 8 + j][dt * 16 + ql];
            *(f16x8*)(Vf + (((size_t)b * 64 + kb * 2 + ktl) * 8 + dt) * 512 + (size_t)l * 8) = r;
        }
    }
}

// ---------------------------------------------------------------------------
// Phase 1: P_b[q][k] = exp2(S_b) / sum_b exp2(S_b), written for ALL 8
// batches in PV-A-fragment-major layout. grid (nq/64)*32, block 512.
// ---------------------------------------------------------------------------
__global__ __launch_bounds__(512, 4)
void zred(const _Float16* __restrict__ Qf, const _Float16* __restrict__ Kf,
          _Float16* __restrict__ Pf, int nqt, int qoff16) {
    __shared__ __attribute__((aligned(16))) _Float16 E[8][64][64];  // 64 KB
    const int bid   = blockIdx.x;
    const int qtile = bid >> 5;          // local to chunk
    const int ktile = bid & 31;
    const int b  = threadIdx.x >> 6;
    const int l  = threadIdx.x & 63;
    const int hi = l >> 4, ql = l & 15;

    const _Float16* Qb = Qf + (size_t)b * QK_BSTRIDE;
    const _Float16* Kb = Kf + (size_t)b * QK_BSTRIDE;

    // swapped S^T = mfma(K, Q): lane holds k = kk*16+hi*4+r, q = qq*16+ql
    f32x4 s[4][4] = {};
    __builtin_amdgcn_s_setprio(1);
#pragma unroll
    for (int ks = 0; ks < 4; ++ks) {
        f16x8 kf[4];
#pragma unroll
        for (int kk = 0; kk < 4; ++kk)
            kf[kk] = *(const f16x8*)(Kb + ((((size_t)ktile * 4 + kk) * 4 + ks) * 64 + l) * 8);
#pragma unroll
        for (int qq = 0; qq < 4; ++qq) {
            f16x8 qv = *(const f16x8*)(Qb + ((((size_t)(qoff16 + qtile * 4 + qq)) * 4 + ks) * 64 + l) * 8);
#pragma unroll
            for (int kk = 0; kk < 4; ++kk)
                s[kk][qq] = __builtin_amdgcn_mfma_f32_16x16x32_f16(kf[kk], qv, s[kk][qq], 0, 0, 0);
        }
    }
    __builtin_amdgcn_s_setprio(0);

    // E[b][q][k] = exp2(S), 16B-granule XOR swizzle on k-group
    f16x4* E4 = (f16x4*)&E[0][0][0];
#pragma unroll
    for (int kk = 0; kk < 4; ++kk)
#pragma unroll
        for (int qq = 0; qq < 4; ++qq) {
            f16x4 e;
#pragma unroll
            for (int r = 0; r < 4; ++r)
                e[r] = (_Float16)fast_exp2(s[kk][qq][r]);
            int q = qq * 16 + ql;
            int k = kk * 16 + hi * 4;
            int g16 = ((b * 64 + q) << 3) + ((k >> 3) ^ (q & 7));
            E4[g16 * 2 + ((k >> 2) & 1)] = e;
        }
    __syncthreads();

    // thread -> PV-A-frag slot: (ktl, qq2, lane)
    const int t    = threadIdx.x;
    const int ktl  = t >> 8;             // 0..1
    const int qq2  = (t >> 6) & 3;       // 0..3
    const int l2   = t & 63;
    const int hi2  = l2 >> 4, ql2 = l2 & 15;
    const int q_loc  = qq2 * 16 + ql2;
    const int k0_loc = ktl * 32 + hi2 * 8;
    const f16x8* E8  = (const f16x8*)&E[0][0][0];
    const int eidx   = (q_loc << 3) + ((k0_loc >> 3) ^ (q_loc & 7));

    // pass 1: z = sum_b e_b
    f16x8 z = E8[eidx];
#pragma unroll
    for (int bb = 1; bb < 8; ++bb) z = z + E8[bb * 512 + eidx];
    float inv[8];
#pragma unroll
    for (int j = 0; j < 8; ++j) inv[j] = __builtin_amdgcn_rcpf((float)z[j]);

    // pass 2: P_b = e_b * inv, coalesced f16x8 store per batch
    const size_t pbase = (((size_t)(qtile * 4 + qq2)) * 64 + (ktile * 2 + ktl)) * 512 + (size_t)l2 * 8;
#pragma unroll
    for (int bb = 0; bb < 8; ++bb) {
        f16x8 e = E8[bb * 512 + eidx];
        f16x8 p;
#pragma unroll
        for (int j = 0; j < 8; ++j) p[j] = (_Float16)((float)e[j] * inv[j]);
        *(f16x8*)(Pf + (size_t)bb * nqt * 32768 + pbase) = p;
    }
}

// ---------------------------------------------------------------------------
// Phase 2: O_b = P_b @ V_b — staged GEMM, global_load_lds TRIPLE-buffer with
// counted vmcnt (depth-2 prefetch; loads stay in flight across barriers).
// grid (nq/64)*8, block 512. Block = (b, 64q); wave = 32q x 32d quadrant.
// K-step 64: stage P 8KB + V 16KB = 24 x 1KB DMA chunks (3 per wave).
// ---------------------------------------------------------------------------
__global__ __launch_bounds__(512)
void av(const _Float16* __restrict__ Pf, const _Float16* __restrict__ Vf,
        float* __restrict__ out, int nqt, int qoff) {
    __shared__ __attribute__((aligned(16))) _Float16 lds[3 * 12288];  // 3 x 24KB

    const int bid = blockIdx.x;
    const int b   = bid & 7;             // batch -> XCD pinned (V_b L2-resident)
    const int mt  = bid >> 3;            // 64-q M-tile (chunk-local)
    const int w   = threadIdx.x >> 6;
    const int l   = threadIdx.x & 63;
    const int wq  = w >> 2;              // 0..1
    const int wd  = w & 3;               // 0..3
    const int hi  = l >> 4, ql = l & 15;

    const _Float16* Pb = Pf + (size_t)b * nqt * 32768;
    const _Float16* Vb = Vf + (size_t)b * VF_BSTRIDE;

#define STAGE(bufi, kt2) do {                                                  \
    _Float16* dst0 = (_Float16*)lds + (size_t)(bufi) * 12288;                  \
    _Pragma("unroll")                                                          \
    for (int u = 0; u < 3; ++u) {                                              \
        int c = w * 3 + u;                                                     \
        const _Float16* srcp;                                                  \
        if (c < 8)                                                             \
            srcp = Pb + (((size_t)(mt * 4 + (c >> 1))) * 64 + ((kt2) * 2 + (c & 1))) * 512 + (size_t)l * 8; \
        else {                                                                 \
            int cv = c - 8;                                                    \
            srcp = Vb + (((size_t)((kt2) * 2 + (cv >> 3))) * 8 + (cv & 7)) * 512 + (size_t)l * 8; \
        }                                                                      \
        dma16(srcp, dst0 + c * 512);                                           \
    }                                                                          \
} while (0)

#define MFMA_PHASE(bufi) do {                                                  \
    const _Float16* Bf = (const _Float16*)lds + (size_t)(bufi) * 12288;        \
    _Pragma("unroll")                                                          \
    for (int ktl = 0; ktl < 2; ++ktl) {                                        \
        f16x8 pfr[2], vfr[2];                                                  \
        _Pragma("unroll")                                                      \
        for (int i = 0; i < 2; ++i)                                            \
            pfr[i] = *(const f16x8*)(Bf + ((wq * 2 + i) * 2 + ktl) * 512 + l * 8); \
        _Pragma("unroll")                                                      \
        for (int j = 0; j < 2; ++j)                                            \
            vfr[j] = *(const f16x8*)(Bf + 4096 + (ktl * 8 + wd * 2 + j) * 512 + l * 8); \
        _Pragma("unroll")                                                      \
        for (int i = 0; i < 2; ++i)                                            \
            _Pragma("unroll")                                                  \
            for (int j = 0; j < 2; ++j)                                        \
                acc[i][j] = __builtin_amdgcn_mfma_f32_16x16x32_f16(pfr[i], vfr[j], acc[i][j], 0, 0, 0); \
    }                                                                          \
} while (0)

    f32x4 acc[2][2] = {};
    STAGE(0, 0);
    STAGE(1, 1);
    for (int kt2 = 0; kt2 < 32; ++kt2) {
        if (kt2 < 30) {
            STAGE((kt2 + 2) % 3, kt2 + 2);
            // stage(kt2) guaranteed done: only kt2+1, kt2+2 (6 loads) remain
            asm volatile("s_waitcnt vmcnt(6)" ::: "memory");
        } else if (kt2 == 30) {
            asm volatile("s_waitcnt vmcnt(3)" ::: "memory");
        } else {
            asm volatile("s_waitcnt vmcnt(0)" ::: "memory");
        }
        __builtin_amdgcn_s_barrier();          // all waves' DMAs for this buf done
        __builtin_amdgcn_sched_barrier(0);     // no ds_read hoisting above
        __builtin_amdgcn_s_setprio(1);
        MFMA_PHASE(kt2 % 3);
        __builtin_amdgcn_s_setprio(0);
        __builtin_amdgcn_s_barrier();          // reads done before buf reuse
    }

    // D-layout: q = +hi*4+r, d = +ql ; each output element written once
    const int q0 = qoff + mt * 64 + wq * 32;
#pragma unroll
    for (int i = 0; i < 2; ++i)
#pragma unroll
        for (int j = 0; j < 2; ++j)
#pragma unroll
            for (int r = 0; r < 4; ++r)
                out[((size_t)b * SQ_ + q0 + i * 16 + hi * 4 + r) * D_ + (wd * 2 + j) * 16 + ql]
                    = acc[i][j][r];
#undef STAGE
#undef MFMA_PHASE
}

// ---------------------------------------------------------------------------
extern "C" void kernel_launch(void* const* d_in, const int* in_sizes, int n_in,
                              void* d_out, int out_size, void* d_ws, size_t ws_size,
                              hipStream_t stream) {
    const float* Q = (const float*)d_in[0];
    const float* K = (const float*)d_in[1];
    const float* V = (const float*)d_in[2];
    float* out = (float*)d_out;

    _Float16* Qf = (_Float16*)d_ws;                       // 4 MB
    _Float16* Kf = Qf + (size_t)B_ * QK_BSTRIDE;          // 4 MB
    _Float16* Vf = Kf + (size_t)B_ * QK_BSTRIDE;          // 4 MB
    _Float16* Pf = Vf + (size_t)B_ * VF_BSTRIDE;          // up to 64 MB

    // fit P-chunk (nq q-rows): nq * 8b * 2048k * 2B = nq * 32KB
    size_t used  = (size_t)(12 * 1024 * 1024);
    size_t avail = ws_size > used ? (ws_size - used) / 2 : 0;   // f16 elems
    int nq = 2048;
    while (nq > 64 && (size_t)nq * 16384 > avail) nq >>= 1;
    int nchunks = 2048 / nq;
    int nqt = nq / 16;

    prep<<<2048 + 256, 256, 0, stream>>>(Q, K, V, Qf, Kf, Vf);

    for (int ci = 0; ci < nchunks; ++ci) {
        int qoff = ci * nq;
        zred<<<(nq / 64) * 32, 512, 0, stream>>>(Qf, Kf, Pf, nqt, qoff >> 4);
        av<<<(nq / 64) * 8, 512, 0, stream>>>(Pf, Vf, out, nqt, qoff);
    }
}

// Round 9
// 57.450 us; speedup vs baseline: 1.1596x; 1.0289x over previous
//
#include <hip/hip_runtime.h>
#include <hip/hip_bf16.h>

#define B_   8
#define SQ_  2048
#define SK_  2048
#define D_   128

typedef __attribute__((ext_vector_type(8))) _Float16 f16x8;
typedef __attribute__((ext_vector_type(4))) _Float16 f16x4;
typedef __attribute__((ext_vector_type(4))) float    f32x4;

// Fragment-major layouts (f16), lane l, hi = l>>4, ql = l&15:
//  Qf[b][qt:128][ks:4][l][8] : elem (q = qt*16+ql, d = ks*32+hi*8+j)  PRE-SCALED log2e/8
//  Kf[b][kt:128][ks:4][l][8] : elem (k = kt*16+ql, d = ks*32+hi*8+j)  PRE-SCALED 1/16
//  Vf[b][kt:64][dt:8][l][8]  : elem (k = kt*32+hi*8+j, d = dt*16+ql)   (B-frag for PV)
//  Pf[b][qtl][kt:64][l][8]   : elem (q = qtl*16+ql, k = kt*32+hi*8+j)  (A-frag for PV)
// => S(mfma) = (Q.K) * log2e/128, so exp(QK/128) = exp2(S): one v_exp_f32.
#define QK_BSTRIDE (128 * 4 * 64 * 8)   // 262144 elems per batch
#define VF_BSTRIDE (64 * 8 * 64 * 8)    // 262144 elems per batch

__device__ __forceinline__ void dma16(const void* g, void* l) {
    __builtin_amdgcn_global_load_lds(
        (const __attribute__((address_space(1))) unsigned int*)g,
        (__attribute__((address_space(3))) unsigned int*)l, 16, 0, 0);
}

__device__ __forceinline__ float fast_exp2(float x) {
#if __has_builtin(__builtin_amdgcn_exp2f)
    return __builtin_amdgcn_exp2f(x);
#else
    return __expf(x * 0.6931471805599453f);
#endif
}

// ---------------------------------------------------------------------------
// prep: blocks 0..511   -> Q,K fp32 -> fragment-major f16 (pre-scaled),
//                          fully-coalesced reads via LDS repack
//       blocks 512..767 -> V fp32 -> PV-B-fragment-major f16
// ---------------------------------------------------------------------------
__global__ __launch_bounds__(256)
void prep(const float* __restrict__ Q, const float* __restrict__ K,
          const float* __restrict__ V,
          _Float16* __restrict__ Qf, _Float16* __restrict__ Kf,
          _Float16* __restrict__ Vf) {
    __shared__ _Float16 T[64][136];
    const int bid = blockIdx.x;
    const int t   = threadIdx.x;
    if (bid < 512) {
        const int tens = bid >> 8;            // 0 = Q, 1 = K
        const float* src = tens ? K : Q;
        _Float16*    dst = tens ? Kf : Qf;
        const float  sc  = tens ? 0.0625f : 0.18033688f;  // 1/16, log2e/8
        const int b  = (bid >> 5) & 7;
        const int rb = bid & 31;              // 64-row block
        const int row = t >> 2, c0 = (t & 3) * 32;
        const float* srow = src + ((size_t)b * 2048 + rb * 64 + row) * 128 + c0;
#pragma unroll
        for (int u = 0; u < 32; u += 4) {
            f32x4 v = *(const f32x4*)(srow + u);
            f16x4 h;
            h[0] = (_Float16)(v[0] * sc); h[1] = (_Float16)(v[1] * sc);
            h[2] = (_Float16)(v[2] * sc); h[3] = (_Float16)(v[3] * sc);
            *(f16x4*)&T[row][c0 + u] = h;
        }
        __syncthreads();
        // 1024 f16x8 chunks in fragment order, contiguous global stores
#pragma unroll
        for (int u = 0; u < 4; ++u) {
            int c  = u * 256 + t;
            int l  = c & 63;
            int ks = (c >> 6) & 3;
            int qt = c >> 8;                  // 0..3
            int hi = l >> 4, ql = l & 15;
            f16x8 r = *(const f16x8*)&T[qt * 16 + ql][ks * 32 + hi * 8];
            *(f16x8*)(dst + ((((size_t)b * 128 + rb * 4 + qt) * 4 + ks) * 64 + l) * 8) = r;
        }
    } else {
        const int vb = bid - 512;             // 0..255
        const int b  = vb >> 5;
        const int kb = vb & 31;
        const int row = t >> 2, c0 = (t & 3) * 32;
        const float* src = V + ((size_t)b * SK_ + kb * 64 + row) * D_ + c0;
#pragma unroll
        for (int u = 0; u < 8; ++u) {
            f32x4 v = *(const f32x4*)(src + u * 4);
            f16x4 h;
            h[0] = (_Float16)v[0]; h[1] = (_Float16)v[1];
            h[2] = (_Float16)v[2]; h[3] = (_Float16)v[3];
            *(f16x4*)&T[row][c0 + u * 4] = h;
        }
        __syncthreads();
#pragma unroll
        for (int u = 0; u < 4; ++u) {
            int s   = u * 256 + t;            // 0..1023
            int l   = s & 63;
            int dt  = (s >> 6) & 7;
            int ktl = s >> 9;                 // 0..1
            int hi  = l >> 4, ql = l & 15;
            f16x8 r;
#pragma unroll
            for (int j = 0; j < 8; ++j) r[j] = T[ktl * 32 + hi * 8 + j][dt * 16 + ql];
            *(f16x8*)(Vf + (((size_t)b * 64 + kb * 2 + ktl) * 8 + dt) * 512 + (size_t)l * 8) = r;
        }
    }
}

// ---------------------------------------------------------------------------
// Phase 1: P_b[q][k] = exp2(S_b) / sum_b exp2(S_b), written for ALL 8
// batches in PV-A-fragment-major layout. grid (nq/64)*32, block 512.
// ---------------------------------------------------------------------------
__global__ __launch_bounds__(512, 4)
void zred(const _Float16* __restrict__ Qf, const _Float16* __restrict__ Kf,
          _Float16* __restrict__ Pf, int nqt, int qoff16) {
    __shared__ __attribute__((aligned(16))) _Float16 E[8][64][64];  // 64 KB
    const int bid   = blockIdx.x;
    const int qtile = bid >> 5;          // local to chunk
    const int ktile = bid & 31;
    const int b  = threadIdx.x >> 6;
    const int l  = threadIdx.x & 63;
    const int hi = l >> 4, ql = l & 15;

    const _Float16* Qb = Qf + (size_t)b * QK_BSTRIDE;
    const _Float16* Kb = Kf + (size_t)b * QK_BSTRIDE;

    // swapped S^T = mfma(K, Q): lane holds k = kk*16+hi*4+r, q = qq*16+ql
    f32x4 s[4][4] = {};
    __builtin_amdgcn_s_setprio(1);
#pragma unroll
    for (int ks = 0; ks < 4; ++ks) {
        f16x8 kf[4];
#pragma unroll
        for (int kk = 0; kk < 4; ++kk)
            kf[kk] = *(const f16x8*)(Kb + ((((size_t)ktile * 4 + kk) * 4 + ks) * 64 + l) * 8);
#pragma unroll
        for (int qq = 0; qq < 4; ++qq) {
            f16x8 qv = *(const f16x8*)(Qb + ((((size_t)(qoff16 + qtile * 4 + qq)) * 4 + ks) * 64 + l) * 8);
#pragma unroll
            for (int kk = 0; kk < 4; ++kk)
                s[kk][qq] = __builtin_amdgcn_mfma_f32_16x16x32_f16(kf[kk], qv, s[kk][qq], 0, 0, 0);
        }
    }
    __builtin_amdgcn_s_setprio(0);

    // E[b][q][k] = exp2(S), 16B-granule XOR swizzle on k-group
    f16x4* E4 = (f16x4*)&E[0][0][0];
#pragma unroll
    for (int kk = 0; kk < 4; ++kk)
#pragma unroll
        for (int qq = 0; qq < 4; ++qq) {
            f16x4 e;
#pragma unroll
            for (int r = 0; r < 4; ++r)
                e[r] = (_Float16)fast_exp2(s[kk][qq][r]);
            int q = qq * 16 + ql;
            int k = kk * 16 + hi * 4;
            int g16 = ((b * 64 + q) << 3) + ((k >> 3) ^ (q & 7));
            E4[g16 * 2 + ((k >> 2) & 1)] = e;
        }
    __syncthreads();

    // thread -> PV-A-frag slot: (ktl, qq2, lane)
    const int t    = threadIdx.x;
    const int ktl  = t >> 8;             // 0..1
    const int qq2  = (t >> 6) & 3;       // 0..3
    const int l2   = t & 63;
    const int hi2  = l2 >> 4, ql2 = l2 & 15;
    const int q_loc  = qq2 * 16 + ql2;
    const int k0_loc = ktl * 32 + hi2 * 8;
    const f16x8* E8  = (const f16x8*)&E[0][0][0];
    const int eidx   = (q_loc << 3) + ((k0_loc >> 3) ^ (q_loc & 7));

    // pass 1: z = sum_b e_b
    f16x8 z = E8[eidx];
#pragma unroll
    for (int bb = 1; bb < 8; ++bb) z = z + E8[bb * 512 + eidx];
    float inv[8];
#pragma unroll
    for (int j = 0; j < 8; ++j) inv[j] = __builtin_amdgcn_rcpf((float)z[j]);

    // pass 2: P_b = e_b * inv, coalesced f16x8 store per batch
    const size_t pbase = (((size_t)(qtile * 4 + qq2)) * 64 + (ktile * 2 + ktl)) * 512 + (size_t)l2 * 8;
#pragma unroll
    for (int bb = 0; bb < 8; ++bb) {
        f16x8 e = E8[bb * 512 + eidx];
        f16x8 p;
#pragma unroll
        for (int j = 0; j < 8; ++j) p[j] = (_Float16)((float)e[j] * inv[j]);
        *(f16x8*)(Pf + (size_t)bb * nqt * 32768 + pbase) = p;
    }
}

// ---------------------------------------------------------------------------
// Phase 2: O_b = P_b @ V_b — staged GEMM, global_load_lds QUAD-buffer,
// prefetch distance 3, counted vmcnt, SINGLE barrier per iteration.
// Overwrite safety: STAGE(it+3) -> buf[(it-1)&3], whose reads were consumed
// by MFMA(it-1) before every wave reached barrier_it (program order + lgkm).
// grid (nq/64)*8, block 512. Block = (b, 64q); wave = 32q x 32d quadrant.
// ---------------------------------------------------------------------------
__global__ __launch_bounds__(512)
void av(const _Float16* __restrict__ Pf, const _Float16* __restrict__ Vf,
        float* __restrict__ out, int nqt, int qoff) {
    __shared__ __attribute__((aligned(16))) _Float16 lds[4 * 12288];  // 4 x 24KB

    const int bid = blockIdx.x;
    const int b   = bid & 7;             // batch -> XCD pinned (V_b L2-resident)
    const int mt  = bid >> 3;            // 64-q M-tile (chunk-local)
    const int w   = threadIdx.x >> 6;
    const int l   = threadIdx.x & 63;
    const int wq  = w >> 2;              // 0..1
    const int wd  = w & 3;               // 0..3
    const int hi  = l >> 4, ql = l & 15;

    const _Float16* Pb = Pf + (size_t)b * nqt * 32768;
    const _Float16* Vb = Vf + (size_t)b * VF_BSTRIDE;

#define STAGE(bufi, kt2) do {                                                  \
    _Float16* dst0 = (_Float16*)lds + (size_t)(bufi) * 12288;                  \
    _Pragma("unroll")                                                          \
    for (int u = 0; u < 3; ++u) {                                              \
        int c = w * 3 + u;                                                     \
        const _Float16* srcp;                                                  \
        if (c < 8)                                                             \
            srcp = Pb + (((size_t)(mt * 4 + (c >> 1))) * 64 + ((kt2) * 2 + (c & 1))) * 512 + (size_t)l * 8; \
        else {                                                                 \
            int cv = c - 8;                                                    \
            srcp = Vb + (((size_t)((kt2) * 2 + (cv >> 3))) * 8 + (cv & 7)) * 512 + (size_t)l * 8; \
        }                                                                      \
        dma16(srcp, dst0 + c * 512);                                           \
    }                                                                          \
} while (0)

#define MFMA_PHASE(bufi) do {                                                  \
    const _Float16* Bf = (const _Float16*)lds + (size_t)(bufi) * 12288;        \
    _Pragma("unroll")                                                          \
    for (int ktl = 0; ktl < 2; ++ktl) {                                        \
        f16x8 pfr[2], vfr[2];                                                  \
        _Pragma("unroll")                                                      \
        for (int i = 0; i < 2; ++i)                                            \
            pfr[i] = *(const f16x8*)(Bf + ((wq * 2 + i) * 2 + ktl) * 512 + l * 8); \
        _Pragma("unroll")                                                      \
        for (int j = 0; j < 2; ++j)                                            \
            vfr[j] = *(const f16x8*)(Bf + 4096 + (ktl * 8 + wd * 2 + j) * 512 + l * 8); \
        _Pragma("unroll")                                                      \
        for (int i = 0; i < 2; ++i)                                            \
            _Pragma("unroll")                                                  \
            for (int j = 0; j < 2; ++j)                                        \
                acc[i][j] = __builtin_amdgcn_mfma_f32_16x16x32_f16(pfr[i], vfr[j], acc[i][j], 0, 0, 0); \
    }                                                                          \
} while (0)

    f32x4 acc[2][2] = {};
    STAGE(0, 0);
    STAGE(1, 1);
    STAGE(2, 2);
    for (int kt2 = 0; kt2 < 32; ++kt2) {
        // stage[kt2] is the oldest in-flight group; <=2 newer groups (6 loads)
        if (kt2 <= 29)      asm volatile("s_waitcnt vmcnt(6)" ::: "memory");
        else if (kt2 == 30) asm volatile("s_waitcnt vmcnt(3)" ::: "memory");
        else                asm volatile("s_waitcnt vmcnt(0)" ::: "memory");
        __builtin_amdgcn_s_barrier();          // all waves' stage[kt2] landed
        __builtin_amdgcn_sched_barrier(0);     // no ds_read hoisting above
        if (kt2 < 29) STAGE((kt2 + 3) & 3, kt2 + 3);
        __builtin_amdgcn_s_setprio(1);
        MFMA_PHASE(kt2 & 3);
        __builtin_amdgcn_s_setprio(0);
    }

    // D-layout: q = +hi*4+r, d = +ql ; each output element written once
    const int q0 = qoff + mt * 64 + wq * 32;
#pragma unroll
    for (int i = 0; i < 2; ++i)
#pragma unroll
        for (int j = 0; j < 2; ++j)
#pragma unroll
            for (int r = 0; r < 4; ++r)
                out[((size_t)b * SQ_ + q0 + i * 16 + hi * 4 + r) * D_ + (wd * 2 + j) * 16 + ql]
                    = acc[i][j][r];
#undef STAGE
#undef MFMA_PHASE
}

// ---------------------------------------------------------------------------
extern "C" void kernel_launch(void* const* d_in, const int* in_sizes, int n_in,
                              void* d_out, int out_size, void* d_ws, size_t ws_size,
                              hipStream_t stream) {
    const float* Q = (const float*)d_in[0];
    const float* K = (const float*)d_in[1];
    const float* V = (const float*)d_in[2];
    float* out = (float*)d_out;

    _Float16* Qf = (_Float16*)d_ws;                       // 4 MB
    _Float16* Kf = Qf + (size_t)B_ * QK_BSTRIDE;          // 4 MB
    _Float16* Vf = Kf + (size_t)B_ * QK_BSTRIDE;          // 4 MB
    _Float16* Pf = Vf + (size_t)B_ * VF_BSTRIDE;          // up to 64 MB

    // fit P-chunk (nq q-rows): nq * 8b * 2048k * 2B = nq * 32KB
    size_t used  = (size_t)(12 * 1024 * 1024);
    size_t avail = ws_size > used ? (ws_size - used) / 2 : 0;   // f16 elems
    int nq = 2048;
    while (nq > 64 && (size_t)nq * 16384 > avail) nq >>= 1;
    int nchunks = 2048 / nq;
    int nqt = nq / 16;

    prep<<<768, 256, 0, stream>>>(Q, K, V, Qf, Kf, Vf);

    for (int ci = 0; ci < nchunks; ++ci) {
        int qoff = ci * nq;
        zred<<<(nq / 64) * 32, 512, 0, stream>>>(Qf, Kf, Pf, nqt, qoff >> 4);
        av<<<(nq / 64) * 8, 512, 0, stream>>>(Pf, Vf, out, nqt, qoff);
    }
}